// Round 1
// baseline (411.748 us; speedup 1.0000x reference)
//
#include <hip/hip_runtime.h>
#include <stdint.h>

#pragma clang fp contract(off)

typedef uint32_t u32;
typedef unsigned long long u64;

#define BN 32
#define NN 8732
#define CC 81
#define KK 200
#define CK (CC * KK)          // 16200
#define TILE 128
#define NTILES 69             // ceil(8732/128)

// ---------------- Kernel 1: decode + clip boxes ----------------
__global__ __launch_bounds__(256) void decode_kernel(
    const float* __restrict__ deltas, const float* __restrict__ priors,
    const float* __restrict__ var, float* __restrict__ boxes) {
  int t = blockIdx.x * 256 + threadIdx.x;
  if (t >= BN * NN) return;
  int n = t % NN;
  float4 d4 = ((const float4*)deltas)[t];
  float4 p = ((const float4*)priors)[n];
  float d0 = d4.x * var[0], d1 = d4.y * var[1];
  float d2 = d4.z * var[2], d3 = d4.w * var[3];
  float ph = p.z - p.x, pw = p.w - p.y;
  float pcy = p.x + 0.5f * ph, pcx = p.y + 0.5f * pw;
  float h = expf(d2) * ph, w = expf(d3) * pw;
  float cy = d0 * ph + pcy, cx = d1 * pw + pcx;
  float y1 = cy - 0.5f * h, x1 = cx - 0.5f * w;
  float y2 = y1 + h, x2 = x1 + w;
  float4 o;
  o.x = fminf(fmaxf(y1, 0.f), 1.f);
  o.y = fminf(fmaxf(x1, 0.f), 1.f);
  o.z = fminf(fmaxf(y2, 0.f), 1.f);
  o.w = fminf(fmaxf(x2, 0.f), 1.f);
  ((float4*)boxes)[t] = o;
}

// ------ Kernel 1b: valid mask (argmax != 0) + transpose to (B,C,N), masked ------
__global__ __launch_bounds__(256) void transpose_valid_kernel(
    const float* __restrict__ labels, float* __restrict__ scores_t) {
  int tile = blockIdx.x % NTILES;
  int b = blockIdx.x / NTILES;
  int n0 = tile * TILE;
  int rows = min(TILE, NN - n0);
  __shared__ float tb[TILE * CC];
  __shared__ float validf[TILE];
  const float* src = labels + ((size_t)b * NN + n0) * CC;
  int total = rows * CC;
  for (int i = threadIdx.x; i < total; i += 256) tb[i] = src[i];
  __syncthreads();
  if (threadIdx.x < rows) {
    const float* r = &tb[threadIdx.x * CC];
    float l0 = r[0];
    float m = r[1];
    for (int c = 2; c < CC; ++c) m = fmaxf(m, r[c]);
    validf[threadIdx.x] = (m > l0) ? 1.f : 0.f;   // argmax != 0
  }
  __syncthreads();
  int half = threadIdx.x >> 7;   // 0/1
  int r0 = threadIdx.x & 127;
  for (int cc = 0; cc < CC + 1; cc += 2) {
    int c = cc + half;
    if (c < CC && r0 < rows)
      scores_t[((size_t)b * CC + c) * NN + n0 + r0] = validf[r0] * tb[r0 * CC + c];
  }
}

// ---------------- Kernel 2: per-(b,c) exact top-200 + greedy NMS ----------------
__global__ __launch_bounds__(256) void class_nms_kernel(
    const float* __restrict__ scores_t, const float* __restrict__ boxes,
    float* __restrict__ sel_s, u32* __restrict__ sel_idx) {
  int bc = blockIdx.x;
  int b = bc / CC;
  int tid = threadIdx.x;
  __shared__ float s_sc[NN];
  __shared__ u32 s_hist[1024];
  __shared__ u64 s_keys[512];
  __shared__ float s_box[KK][4];
  __shared__ u64 s_row[KK][4];
  __shared__ u64 s_keep[4];
  __shared__ u32 s_vstar, s_m;

  const float* src = scores_t + (size_t)bc * NN;
  for (int i = tid; i < NN; i += 256) s_sc[i] = src[i];
  for (int i = tid; i < 1024; i += 256) s_hist[i] = 0;
  for (int i = tid; i < 512; i += 256) s_keys[i] = 0;
  if (tid == 0) s_m = 0;
  __syncthreads();

  // histogram over scores >= 0.5 on mantissa bits [22:13] (uniform bins in [0.5,1))
  for (int i = tid; i < NN; i += 256) {
    u32 bits = __float_as_uint(s_sc[i]);
    if (bits >= 0x3F000000u) {
      u32 bin = (bits >= 0x3F800000u) ? 1023u : ((bits >> 13) & 1023u);
      atomicAdd(&s_hist[bin], 1u);
    }
  }
  __syncthreads();
  // suffix sum (Hillis-Steele)
  for (int d = 1; d < 1024; d <<= 1) {
    u32 t0[4];
#pragma unroll
    for (int k = 0; k < 4; ++k) {
      int v = tid + k * 256;
      t0[k] = s_hist[v] + ((v + d < 1024) ? s_hist[v + d] : 0);
    }
    __syncthreads();
#pragma unroll
    for (int k = 0; k < 4; ++k) s_hist[tid + k * 256] = t0[k];
    __syncthreads();
  }
  // vstar = max v with S[v] >= K (else 0)
#pragma unroll
  for (int k = 0; k < 4; ++k) {
    int v = tid + k * 256;
    u32 Sv = s_hist[v];
    u32 Snext = (v < 1023) ? s_hist[v + 1] : 0;
    bool cond = (Sv >= KK && (v == 1023 || Snext < KK)) || (v == 0 && s_hist[0] < KK);
    if (cond) s_vstar = (u32)v;
  }
  __syncthreads();
  u32 vstar = s_vstar;
  // compact candidates in bins >= vstar (64-bit exact keys)
  for (int i = tid; i < NN; i += 256) {
    u32 bits = __float_as_uint(s_sc[i]);
    if (bits >= 0x3F000000u) {
      u32 bin = (bits >= 0x3F800000u) ? 1023u : ((bits >> 13) & 1023u);
      if (bin >= vstar) {
        u32 pos = atomicAdd(&s_m, 1u);
        if (pos < 512) s_keys[pos] = ((u64)bits << 32) | (u64)(0xFFFFFFFFu - (u32)i);
      }
    }
  }
  __syncthreads();
  // bitonic sort 512 descending (pads are key 0)
  for (int k = 2; k <= 512; k <<= 1) {
    for (int j = k >> 1; j > 0; j >>= 1) {
      for (int i = tid; i < 512; i += 256) {
        int l = i ^ j;
        if (l > i) {
          u64 a = s_keys[i], c2 = s_keys[l];
          bool up = ((i & k) == 0);
          if (up ? (a < c2) : (a > c2)) { s_keys[i] = c2; s_keys[l] = a; }
        }
      }
      __syncthreads();
    }
  }
  // gather top-200 boxes
  for (int i = tid; i < KK; i += 256) {
    u64 key = s_keys[i];
    u32 n = 0xFFFFFFFFu - (u32)(key & 0xFFFFFFFFull);
    float4 bx = make_float4(0.f, 0.f, 0.f, 0.f);
    if (key != 0 && n < NN) bx = ((const float4*)boxes)[(size_t)b * NN + n];
    s_box[i][0] = bx.x; s_box[i][1] = bx.y; s_box[i][2] = bx.z; s_box[i][3] = bx.w;
  }
  __syncthreads();
  // suppression bitmask rows (j < i only)
  for (int task = tid; task < KK * 4; task += 256) {
    int i = task >> 2, jw = task & 3;
    int jb = jw << 6;
    u64 m = 0;
    if (jb < i) {
      float y1i = s_box[i][0], x1i = s_box[i][1], y2i = s_box[i][2], x2i = s_box[i][3];
      float ai = (y2i - y1i) * (x2i - x1i);
      int je = min(jb + 64, i);
      for (int j = jb; j < je; ++j) {
        float y1j = s_box[j][0], x1j = s_box[j][1], y2j = s_box[j][2], x2j = s_box[j][3];
        float aj = (y2j - y1j) * (x2j - x1j);
        float iy1 = fmaxf(y1i, y1j), ix1 = fmaxf(x1i, x1j);
        float iy2 = fminf(y2i, y2j), ix2 = fminf(x2i, x2j);
        float inter = fmaxf(iy2 - iy1, 0.f) * fmaxf(ix2 - ix1, 0.f);
        float uni = ai + aj - inter;
        float iou = inter / fmaxf(uni, 1e-8f);
        if (iou > 0.5f) m |= 1ull << (j - jb);
      }
    }
    s_row[i][jw] = m;
  }
  __syncthreads();
  // register-resident greedy, wave 0; lane l owns rows l, 64+l, 128+l, 192+l
  if (tid < 64) {
    int l = tid;
    u64 r0_0 = s_row[l][0], r0_1 = s_row[l][1], r0_2 = s_row[l][2], r0_3 = s_row[l][3];
    u64 r1_0 = s_row[64 + l][0], r1_1 = s_row[64 + l][1], r1_2 = s_row[64 + l][2], r1_3 = s_row[64 + l][3];
    u64 r2_0 = s_row[128 + l][0], r2_1 = s_row[128 + l][1], r2_2 = s_row[128 + l][2], r2_3 = s_row[128 + l][3];
    u64 r3_0 = 0, r3_1 = 0, r3_2 = 0, r3_3 = 0;
    bool v0 = __uint_as_float((u32)(s_keys[l] >> 32)) > 0.5f;
    bool v1 = __uint_as_float((u32)(s_keys[64 + l] >> 32)) > 0.5f;
    bool v2 = __uint_as_float((u32)(s_keys[128 + l] >> 32)) > 0.5f;
    bool v3 = false;
    if (l < KK - 192) {
      r3_0 = s_row[192 + l][0]; r3_1 = s_row[192 + l][1];
      r3_2 = s_row[192 + l][2]; r3_3 = s_row[192 + l][3];
      v3 = __uint_as_float((u32)(s_keys[192 + l] >> 32)) > 0.5f;
    }
    u64 k0 = 0, k1 = 0, k2 = 0, k3 = 0;
    for (int srcl = 0; srcl < 64; ++srcl) {
      u64 sup = (k0 & r0_0) | (k1 & r0_1) | (k2 & r0_2) | (k3 & r0_3);
      int kil = (v0 && sup == 0) ? 1 : 0;
      int ki = __shfl(kil, srcl, 64);
      k0 |= ((u64)ki) << srcl;
    }
    for (int srcl = 0; srcl < 64; ++srcl) {
      u64 sup = (k0 & r1_0) | (k1 & r1_1) | (k2 & r1_2) | (k3 & r1_3);
      int kil = (v1 && sup == 0) ? 1 : 0;
      int ki = __shfl(kil, srcl, 64);
      k1 |= ((u64)ki) << srcl;
    }
    for (int srcl = 0; srcl < 64; ++srcl) {
      u64 sup = (k0 & r2_0) | (k1 & r2_1) | (k2 & r2_2) | (k3 & r2_3);
      int kil = (v2 && sup == 0) ? 1 : 0;
      int ki = __shfl(kil, srcl, 64);
      k2 |= ((u64)ki) << srcl;
    }
    for (int srcl = 0; srcl < KK - 192; ++srcl) {
      u64 sup = (k0 & r3_0) | (k1 & r3_1) | (k2 & r3_2) | (k3 & r3_3);
      int kil = (v3 && sup == 0) ? 1 : 0;
      int ki = __shfl(kil, srcl, 64);
      k3 |= ((u64)ki) << srcl;
    }
    if (l == 0) { s_keep[0] = k0; s_keep[1] = k1; s_keep[2] = k2; s_keep[3] = k3; }
  }
  __syncthreads();
  // write selections
  for (int i = tid; i < KK; i += 256) {
    u64 key = s_keys[i];
    float sc = __uint_as_float((u32)(key >> 32));
    u32 n = 0xFFFFFFFFu - (u32)(key & 0xFFFFFFFFull);
    bool kept = (s_keep[i >> 6] >> (i & 63)) & 1ull;
    size_t o = (size_t)bc * KK + i;
    sel_s[o] = kept ? sc : 0.f;
    sel_idx[o] = (key != 0 && n < NN) ? n : 0u;
  }
}

// ---------------- Kernel 3: final per-batch top-200 ----------------
__global__ __launch_bounds__(256) void final_topk_kernel(
    const float* __restrict__ sel_s, const u32* __restrict__ sel_idx,
    const float* __restrict__ boxes, float* __restrict__ out) {
  int b = blockIdx.x;
  int tid = threadIdx.x;
  __shared__ u32 s_hist[1024];
  __shared__ u64 s_keys[2048];
  __shared__ u32 s_vstar, s_m;
  const float* src = sel_s + (size_t)b * CK;
  for (int i = tid; i < 1024; i += 256) s_hist[i] = 0;
  for (int i = tid; i < 2048; i += 256) s_keys[i] = 0;
  if (tid == 0) s_m = 0;
  __syncthreads();
  for (int i = tid; i < CK; i += 256) {
    u32 bits = __float_as_uint(src[i]);
    if (bits >= 0x3F000000u) {
      u32 bin = (bits >= 0x3F800000u) ? 1023u : ((bits >> 13) & 1023u);
      atomicAdd(&s_hist[bin], 1u);
    }
  }
  __syncthreads();
  for (int d = 1; d < 1024; d <<= 1) {
    u32 t0[4];
#pragma unroll
    for (int k = 0; k < 4; ++k) {
      int v = tid + k * 256;
      t0[k] = s_hist[v] + ((v + d < 1024) ? s_hist[v + d] : 0);
    }
    __syncthreads();
#pragma unroll
    for (int k = 0; k < 4; ++k) s_hist[tid + k * 256] = t0[k];
    __syncthreads();
  }
#pragma unroll
  for (int k = 0; k < 4; ++k) {
    int v = tid + k * 256;
    u32 Sv = s_hist[v];
    u32 Snext = (v < 1023) ? s_hist[v + 1] : 0;
    bool cond = (Sv >= KK && (v == 1023 || Snext < KK)) || (v == 0 && s_hist[0] < KK);
    if (cond) s_vstar = (u32)v;
  }
  __syncthreads();
  u32 vstar = s_vstar;
  for (int i = tid; i < CK; i += 256) {
    u32 bits = __float_as_uint(src[i]);
    if (bits >= 0x3F000000u) {
      u32 bin = (bits >= 0x3F800000u) ? 1023u : ((bits >> 13) & 1023u);
      if (bin >= vstar) {
        u32 pos = atomicAdd(&s_m, 1u);
        if (pos < 2048) s_keys[pos] = ((u64)bits << 32) | (u64)(0xFFFFFFFFu - (u32)i);
      }
    }
  }
  __syncthreads();
  for (int k = 2; k <= 2048; k <<= 1) {
    for (int j = k >> 1; j > 0; j >>= 1) {
      for (int i = tid; i < 2048; i += 256) {
        int l = i ^ j;
        if (l > i) {
          u64 a = s_keys[i], c2 = s_keys[l];
          bool up = ((i & k) == 0);
          if (up ? (a < c2) : (a > c2)) { s_keys[i] = c2; s_keys[l] = a; }
        }
      }
      __syncthreads();
    }
  }
  for (int i = tid; i < KK; i += 256) {
    u64 key = s_keys[i];
    float sc = __uint_as_float((u32)(key >> 32));
    u32 flat = 0xFFFFFFFFu - (u32)(key & 0xFFFFFFFFull);
    float4 bx = make_float4(0.f, 0.f, 0.f, 0.f);
    float lab = 0.f;
    if (key != 0 && flat < CK) {
      u32 n = sel_idx[(size_t)b * CK + flat];
      bx = ((const float4*)boxes)[(size_t)b * NN + n];
      lab = (float)(flat / KK);
    }
    ((float4*)out)[(size_t)b * KK + i] = bx;
    out[BN * KK * 4 + (size_t)b * KK + i] = sc;
    out[BN * KK * 5 + (size_t)b * KK + i] = (sc > 0.f) ? lab : 0.f;
  }
}

extern "C" void kernel_launch(void* const* d_in, const int* in_sizes, int n_in,
                              void* d_out, int out_size, void* d_ws, size_t ws_size,
                              hipStream_t stream) {
  const float* deltas = (const float*)d_in[0];
  const float* labels = (const float*)d_in[1];
  const float* priors = (const float*)d_in[2];
  const float* var = (const float*)d_in[3];
  float* out = (float*)d_out;
  char* ws = (char*)d_ws;
  size_t boxesB = (size_t)BN * NN * 4 * 4;        //  4,470,784
  size_t scoresB = (size_t)BN * CC * NN * 4;      // 90,533,376
  size_t selB = (size_t)BN * CC * KK * 4;         //  2,073,600
  float* boxes = (float*)ws;
  float* scores_t = (float*)(ws + boxesB);
  float* sel_s = (float*)(ws + boxesB + scoresB);
  u32* sel_idx = (u32*)(ws + boxesB + scoresB + selB);

  decode_kernel<<<(BN * NN + 255) / 256, 256, 0, stream>>>(deltas, priors, var, boxes);
  transpose_valid_kernel<<<BN * NTILES, 256, 0, stream>>>(labels, scores_t);
  class_nms_kernel<<<BN * CC, 256, 0, stream>>>(scores_t, boxes, sel_s, sel_idx);
  final_topk_kernel<<<BN, 256, 0, stream>>>(sel_s, sel_idx, boxes, out);
}

// Round 2
// 275.481 us; speedup vs baseline: 1.4947x; 1.4947x over previous
//
#include <hip/hip_runtime.h>
#include <stdint.h>

#pragma clang fp contract(off)

typedef uint32_t u32;
typedef unsigned long long u64;

#define BN 32
#define NN 8732
#define CC 81
#define KK 200
#define CK (CC * KK)          // 16200
#define TILE 128
#define NTILES 69             // ceil(8732/128)

// ---------------- Kernel 1: decode + clip boxes ----------------
__global__ __launch_bounds__(256) void decode_kernel(
    const float* __restrict__ deltas, const float* __restrict__ priors,
    const float* __restrict__ var, float* __restrict__ boxes) {
  int t = blockIdx.x * 256 + threadIdx.x;
  if (t >= BN * NN) return;
  int n = t % NN;
  float4 d4 = ((const float4*)deltas)[t];
  float4 p = ((const float4*)priors)[n];
  float d0 = d4.x * var[0], d1 = d4.y * var[1];
  float d2 = d4.z * var[2], d3 = d4.w * var[3];
  float ph = p.z - p.x, pw = p.w - p.y;
  float pcy = p.x + 0.5f * ph, pcx = p.y + 0.5f * pw;
  float h = expf(d2) * ph, w = expf(d3) * pw;
  float cy = d0 * ph + pcy, cx = d1 * pw + pcx;
  float y1 = cy - 0.5f * h, x1 = cx - 0.5f * w;
  float y2 = y1 + h, x2 = x1 + w;
  float4 o;
  o.x = fminf(fmaxf(y1, 0.f), 1.f);
  o.y = fminf(fmaxf(x1, 0.f), 1.f);
  o.z = fminf(fmaxf(y2, 0.f), 1.f);
  o.w = fminf(fmaxf(x2, 0.f), 1.f);
  ((float4*)boxes)[t] = o;
}

// ------ Kernel 1b: valid mask (argmax != 0) + transpose to (B,C,N), masked ------
__global__ __launch_bounds__(256) void transpose_valid_kernel(
    const float* __restrict__ labels, float* __restrict__ scores_t) {
  int tile = blockIdx.x % NTILES;
  int b = blockIdx.x / NTILES;
  int n0 = tile * TILE;
  int rows = min(TILE, NN - n0);      // 128 or 28 (both divisible by 4)
  __shared__ float tb[TILE * CC];
  __shared__ float validf[TILE];
  const float* src = labels + ((size_t)b * NN + n0) * CC;
  // float4 loads: offset (b*8732 + n0)*81 is divisible by 4 for all b, n0
  const float4* src4 = (const float4*)src;
  int total4 = (rows * CC) >> 2;      // rows*81 divisible by 4
  for (int i = threadIdx.x; i < total4; i += 256) ((float4*)tb)[i] = src4[i];
  __syncthreads();
  if (threadIdx.x < rows) {
    const float* r = &tb[threadIdx.x * CC];
    float l0 = r[0];
    float m = r[1];
    for (int c = 2; c < CC; ++c) m = fmaxf(m, r[c]);
    validf[threadIdx.x] = (m > l0) ? 1.f : 0.f;   // argmax != 0
  }
  __syncthreads();
  // float4 stores: 8 classes at a time, 32 threads x float4 per class
  int c0 = threadIdx.x >> 5;   // 0..7
  int nq = threadIdx.x & 31;   // 0..31
  int r = nq * 4;
  for (int cb = 0; cb < CC; cb += 8) {
    int c = cb + c0;
    if (c < CC && r < rows) {
      float4 v;
      v.x = validf[r + 0] * tb[(r + 0) * CC + c];
      v.y = validf[r + 1] * tb[(r + 1) * CC + c];
      v.z = validf[r + 2] * tb[(r + 2) * CC + c];
      v.w = validf[r + 3] * tb[(r + 3) * CC + c];
      // NN and n0 divisible by 4 -> aligned
      *(float4*)&scores_t[((size_t)b * CC + c) * NN + n0 + r] = v;
    }
  }
}

// ---------------- Kernel 2: per-(b,c) exact top-200 + greedy NMS ----------------
// Scores are read from global twice (L3-resident) instead of LDS staging:
// LDS 53KB -> ~19KB, occupancy 3 -> 8 blocks/CU.
__global__ __launch_bounds__(256) void class_nms_kernel(
    const float* __restrict__ scores_t, const float* __restrict__ boxes,
    float* __restrict__ sel_s, u32* __restrict__ sel_idx) {
  int bc = blockIdx.x;
  int b = bc / CC;
  int tid = threadIdx.x;
  __shared__ u32 s_hist[1024];
  __shared__ u64 s_keys[512];
  __shared__ float s_box[KK][4];
  __shared__ float s_area[KK];
  __shared__ u64 s_row[KK][4];
  __shared__ u64 s_keep[4];
  __shared__ u32 s_vstar, s_m;

  const float* src = scores_t + (size_t)bc * NN;
  for (int i = tid; i < 1024; i += 256) s_hist[i] = 0;
  for (int i = tid; i < 512; i += 256) s_keys[i] = 0;
  if (tid == 0) s_m = 0;
  __syncthreads();

  // histogram over scores >= 0.5 on mantissa bits [22:13] (uniform bins in [0.5,1))
  for (int i = tid; i < NN; i += 256) {
    u32 bits = __float_as_uint(src[i]);
    if (bits >= 0x3F000000u) {
      u32 bin = (bits >= 0x3F800000u) ? 1023u : ((bits >> 13) & 1023u);
      atomicAdd(&s_hist[bin], 1u);
    }
  }
  __syncthreads();
  // suffix sum (Hillis-Steele)
  for (int d = 1; d < 1024; d <<= 1) {
    u32 t0[4];
#pragma unroll
    for (int k = 0; k < 4; ++k) {
      int v = tid + k * 256;
      t0[k] = s_hist[v] + ((v + d < 1024) ? s_hist[v + d] : 0);
    }
    __syncthreads();
#pragma unroll
    for (int k = 0; k < 4; ++k) s_hist[tid + k * 256] = t0[k];
    __syncthreads();
  }
  // vstar = max v with S[v] >= K (else 0)
#pragma unroll
  for (int k = 0; k < 4; ++k) {
    int v = tid + k * 256;
    u32 Sv = s_hist[v];
    u32 Snext = (v < 1023) ? s_hist[v + 1] : 0;
    bool cond = (Sv >= KK && (v == 1023 || Snext < KK)) || (v == 0 && s_hist[0] < KK);
    if (cond) s_vstar = (u32)v;
  }
  __syncthreads();
  u32 vstar = s_vstar;
  // compact candidates in bins >= vstar (64-bit exact keys)
  for (int i = tid; i < NN; i += 256) {
    u32 bits = __float_as_uint(src[i]);
    if (bits >= 0x3F000000u) {
      u32 bin = (bits >= 0x3F800000u) ? 1023u : ((bits >> 13) & 1023u);
      if (bin >= vstar) {
        u32 pos = atomicAdd(&s_m, 1u);
        if (pos < 512) s_keys[pos] = ((u64)bits << 32) | (u64)(0xFFFFFFFFu - (u32)i);
      }
    }
  }
  __syncthreads();
  // bitonic sort 512 descending (pads are key 0)
  for (int k = 2; k <= 512; k <<= 1) {
    for (int j = k >> 1; j > 0; j >>= 1) {
      for (int i = tid; i < 512; i += 256) {
        int l = i ^ j;
        if (l > i) {
          u64 a = s_keys[i], c2 = s_keys[l];
          bool up = ((i & k) == 0);
          if (up ? (a < c2) : (a > c2)) { s_keys[i] = c2; s_keys[l] = a; }
        }
      }
      __syncthreads();
    }
  }
  // gather top-200 boxes
  for (int i = tid; i < KK; i += 256) {
    u64 key = s_keys[i];
    u32 n = 0xFFFFFFFFu - (u32)(key & 0xFFFFFFFFull);
    float4 bx = make_float4(0.f, 0.f, 0.f, 0.f);
    if (key != 0 && n < NN) bx = ((const float4*)boxes)[(size_t)b * NN + n];
    s_box[i][0] = bx.x; s_box[i][1] = bx.y; s_box[i][2] = bx.z; s_box[i][3] = bx.w;
    s_area[i] = (bx.z - bx.x) * (bx.w - bx.y);
  }
  __syncthreads();
  // suppression bitmask rows (j < i only)
  for (int task = tid; task < KK * 4; task += 256) {
    int i = task >> 2, jw = task & 3;
    int jb = jw << 6;
    u64 m = 0;
    if (jb < i) {
      float y1i = s_box[i][0], x1i = s_box[i][1], y2i = s_box[i][2], x2i = s_box[i][3];
      float ai = s_area[i];
      int je = min(jb + 64, i);
      for (int j = jb; j < je; ++j) {
        float y1j = s_box[j][0], x1j = s_box[j][1], y2j = s_box[j][2], x2j = s_box[j][3];
        float aj = s_area[j];
        float iy1 = fmaxf(y1i, y1j), ix1 = fmaxf(x1i, x1j);
        float iy2 = fminf(y2i, y2j), ix2 = fminf(x2i, x2j);
        float inter = fmaxf(iy2 - iy1, 0.f) * fmaxf(ix2 - ix1, 0.f);
        float uni = ai + aj - inter;
        float iou = inter / fmaxf(uni, 1e-8f);
        if (iou > 0.5f) m |= 1ull << (j - jb);
      }
    }
    s_row[i][jw] = m;
  }
  __syncthreads();
  // register-resident greedy, wave 0; lane l owns rows l, 64+l, 128+l, 192+l
  if (tid < 64) {
    int l = tid;
    u64 r0_0 = s_row[l][0], r0_1 = s_row[l][1], r0_2 = s_row[l][2], r0_3 = s_row[l][3];
    u64 r1_0 = s_row[64 + l][0], r1_1 = s_row[64 + l][1], r1_2 = s_row[64 + l][2], r1_3 = s_row[64 + l][3];
    u64 r2_0 = s_row[128 + l][0], r2_1 = s_row[128 + l][1], r2_2 = s_row[128 + l][2], r2_3 = s_row[128 + l][3];
    u64 r3_0 = 0, r3_1 = 0, r3_2 = 0, r3_3 = 0;
    bool v0 = __uint_as_float((u32)(s_keys[l] >> 32)) > 0.5f;
    bool v1 = __uint_as_float((u32)(s_keys[64 + l] >> 32)) > 0.5f;
    bool v2 = __uint_as_float((u32)(s_keys[128 + l] >> 32)) > 0.5f;
    bool v3 = false;
    if (l < KK - 192) {
      r3_0 = s_row[192 + l][0]; r3_1 = s_row[192 + l][1];
      r3_2 = s_row[192 + l][2]; r3_3 = s_row[192 + l][3];
      v3 = __uint_as_float((u32)(s_keys[192 + l] >> 32)) > 0.5f;
    }
    u64 k0 = 0, k1 = 0, k2 = 0, k3 = 0;
    for (int srcl = 0; srcl < 64; ++srcl) {
      u64 sup = (k0 & r0_0) | (k1 & r0_1) | (k2 & r0_2) | (k3 & r0_3);
      int kil = (v0 && sup == 0) ? 1 : 0;
      int ki = __shfl(kil, srcl, 64);
      k0 |= ((u64)ki) << srcl;
    }
    for (int srcl = 0; srcl < 64; ++srcl) {
      u64 sup = (k0 & r1_0) | (k1 & r1_1) | (k2 & r1_2) | (k3 & r1_3);
      int kil = (v1 && sup == 0) ? 1 : 0;
      int ki = __shfl(kil, srcl, 64);
      k1 |= ((u64)ki) << srcl;
    }
    for (int srcl = 0; srcl < 64; ++srcl) {
      u64 sup = (k0 & r2_0) | (k1 & r2_1) | (k2 & r2_2) | (k3 & r2_3);
      int kil = (v2 && sup == 0) ? 1 : 0;
      int ki = __shfl(kil, srcl, 64);
      k2 |= ((u64)ki) << srcl;
    }
    for (int srcl = 0; srcl < KK - 192; ++srcl) {
      u64 sup = (k0 & r3_0) | (k1 & r3_1) | (k2 & r3_2) | (k3 & r3_3);
      int kil = (v3 && sup == 0) ? 1 : 0;
      int ki = __shfl(kil, srcl, 64);
      k3 |= ((u64)ki) << srcl;
    }
    if (l == 0) { s_keep[0] = k0; s_keep[1] = k1; s_keep[2] = k2; s_keep[3] = k3; }
  }
  __syncthreads();
  // write selections
  for (int i = tid; i < KK; i += 256) {
    u64 key = s_keys[i];
    float sc = __uint_as_float((u32)(key >> 32));
    u32 n = 0xFFFFFFFFu - (u32)(key & 0xFFFFFFFFull);
    bool kept = (s_keep[i >> 6] >> (i & 63)) & 1ull;
    size_t o = (size_t)bc * KK + i;
    sel_s[o] = kept ? sc : 0.f;
    sel_idx[o] = (key != 0 && n < NN) ? n : 0u;
  }
}

// ---------------- Kernel 3: final per-batch top-200 (1024 threads) ----------------
__global__ __launch_bounds__(1024) void final_topk_kernel(
    const float* __restrict__ sel_s, const u32* __restrict__ sel_idx,
    const float* __restrict__ boxes, float* __restrict__ out) {
  int b = blockIdx.x;
  int tid = threadIdx.x;
  __shared__ u32 s_hist[1024];
  __shared__ u64 s_keys[2048];
  __shared__ u32 s_vstar, s_m;
  const float* src = sel_s + (size_t)b * CK;
  s_hist[tid] = 0;
  s_keys[tid] = 0;
  s_keys[tid + 1024] = 0;
  if (tid == 0) s_m = 0;
  __syncthreads();
  for (int i = tid; i < CK; i += 1024) {
    u32 bits = __float_as_uint(src[i]);
    if (bits >= 0x3F000000u) {
      u32 bin = (bits >= 0x3F800000u) ? 1023u : ((bits >> 13) & 1023u);
      atomicAdd(&s_hist[bin], 1u);
    }
  }
  __syncthreads();
  for (int d = 1; d < 1024; d <<= 1) {
    u32 t0 = s_hist[tid] + ((tid + d < 1024) ? s_hist[tid + d] : 0);
    __syncthreads();
    s_hist[tid] = t0;
    __syncthreads();
  }
  {
    int v = tid;
    u32 Sv = s_hist[v];
    u32 Snext = (v < 1023) ? s_hist[v + 1] : 0;
    bool cond = (Sv >= KK && (v == 1023 || Snext < KK)) || (v == 0 && s_hist[0] < KK);
    if (cond) s_vstar = (u32)v;
  }
  __syncthreads();
  u32 vstar = s_vstar;
  for (int i = tid; i < CK; i += 1024) {
    u32 bits = __float_as_uint(src[i]);
    if (bits >= 0x3F000000u) {
      u32 bin = (bits >= 0x3F800000u) ? 1023u : ((bits >> 13) & 1023u);
      if (bin >= vstar) {
        u32 pos = atomicAdd(&s_m, 1u);
        if (pos < 2048) s_keys[pos] = ((u64)bits << 32) | (u64)(0xFFFFFFFFu - (u32)i);
      }
    }
  }
  __syncthreads();
  for (int k = 2; k <= 2048; k <<= 1) {
    for (int j = k >> 1; j > 0; j >>= 1) {
      for (int i = tid; i < 2048; i += 1024) {
        int l = i ^ j;
        if (l > i) {
          u64 a = s_keys[i], c2 = s_keys[l];
          bool up = ((i & k) == 0);
          if (up ? (a < c2) : (a > c2)) { s_keys[i] = c2; s_keys[l] = a; }
        }
      }
      __syncthreads();
    }
  }
  if (tid < KK) {
    int i = tid;
    u64 key = s_keys[i];
    float sc = __uint_as_float((u32)(key >> 32));
    u32 flat = 0xFFFFFFFFu - (u32)(key & 0xFFFFFFFFull);
    float4 bx = make_float4(0.f, 0.f, 0.f, 0.f);
    float lab = 0.f;
    if (key != 0 && flat < CK) {
      u32 n = sel_idx[(size_t)b * CK + flat];
      bx = ((const float4*)boxes)[(size_t)b * NN + n];
      lab = (float)(flat / KK);
    }
    ((float4*)out)[(size_t)b * KK + i] = bx;
    out[BN * KK * 4 + (size_t)b * KK + i] = sc;
    out[BN * KK * 5 + (size_t)b * KK + i] = (sc > 0.f) ? lab : 0.f;
  }
}

extern "C" void kernel_launch(void* const* d_in, const int* in_sizes, int n_in,
                              void* d_out, int out_size, void* d_ws, size_t ws_size,
                              hipStream_t stream) {
  const float* deltas = (const float*)d_in[0];
  const float* labels = (const float*)d_in[1];
  const float* priors = (const float*)d_in[2];
  const float* var = (const float*)d_in[3];
  float* out = (float*)d_out;
  char* ws = (char*)d_ws;
  size_t boxesB = (size_t)BN * NN * 4 * 4;        //  4,470,784
  size_t scoresB = (size_t)BN * CC * NN * 4;      // 90,533,376
  size_t selB = (size_t)BN * CC * KK * 4;         //  2,073,600
  float* boxes = (float*)ws;
  float* scores_t = (float*)(ws + boxesB);
  float* sel_s = (float*)(ws + boxesB + scoresB);
  u32* sel_idx = (u32*)(ws + boxesB + scoresB + selB);

  decode_kernel<<<(BN * NN + 255) / 256, 256, 0, stream>>>(deltas, priors, var, boxes);
  transpose_valid_kernel<<<BN * NTILES, 256, 0, stream>>>(labels, scores_t);
  class_nms_kernel<<<BN * CC, 256, 0, stream>>>(scores_t, boxes, sel_s, sel_idx);
  final_topk_kernel<<<BN, 1024, 0, stream>>>(sel_s, sel_idx, boxes, out);
}